// Round 1
// baseline (27.277 us; speedup 1.0000x reference)
//
#include <hip/hip_runtime.h>
#include <hip/hip_bf16.h>

// AngleTensor: out[b,i,j,k] = mask * arccos( (p_j - p_i) . (p_k - p_i) / (d_ij * d_ik) )
// mask = 0 when i==j || i==k || j==k; mag < 1e-10 -> mag = 1.
// positions: (B,N,3) f32, dist: (B,N,N) f32, out: (B,N,N,N) f32.

#define EPSV 1e-10f
#define PI_F 3.14159265358979323846f

// Abramowitz-Stegun 4.4.45: |err| <= ~7e-5 rad on [0,1]; reflected for x<0.
__device__ __forceinline__ float fast_acos(float x) {
    float ax = fabsf(x);
    float p = fmaf(ax, -0.0187293f, 0.0742610f);
    p = fmaf(ax, p, -0.2121144f);
    p = fmaf(ax, p, 1.5707288f);
    float s = sqrtf(fmaxf(1.0f - ax, 0.0f));
    float r = s * p;
    return (x < 0.0f) ? (PI_F - r) : r;
}

__device__ __forceinline__ float angle_one(float ex, float ey, float ez,
                                           float fx, float fy, float fz,
                                           float dij, float dik,
                                           int i, int j, int k) {
    float dot = fmaf(ex, fx, fmaf(ey, fy, ez * fz));
    float mag = dij * dik;
    mag = (mag < EPSV) ? 1.0f : mag;
    float c = dot * __builtin_amdgcn_rcpf(mag);
    c = fminf(fmaxf(c, -1.0f), 1.0f);
    float ang = fast_acos(c);
    bool msk = (i != j) && (i != k) && (j != k);
    return msk ? ang : 0.0f;
}

// Vectorized kernel: requires N % 4 == 0.
// block = 256 threads: tid = jj*32 + kq; jj in [0,8), kq in [0,32).
// grid = (ceil(N/8), N, B). Each thread: 4 consecutive k per loop iter, float4 store.
__global__ __launch_bounds__(256) void angle_vec4(const float* __restrict__ pos,
                                                  const float* __restrict__ dist,
                                                  float* __restrict__ out, int N) {
    const int kq = threadIdx.x & 31;
    const int jj = threadIdx.x >> 5;
    const int j  = blockIdx.x * 8 + jj;
    const int i  = blockIdx.y;
    const int b  = blockIdx.z;
    if (j >= N) return;

    const float* pb   = pos  + (size_t)b * N * 3;
    const float* drow = dist + ((size_t)b * N + i) * N;

    const float pix = pb[i * 3 + 0];
    const float piy = pb[i * 3 + 1];
    const float piz = pb[i * 3 + 2];
    const float ex  = pb[j * 3 + 0] - pix;
    const float ey  = pb[j * 3 + 1] - piy;
    const float ez  = pb[j * 3 + 2] - piz;
    const float dij = drow[j];

    float* orow = out + (((size_t)b * N + i) * N + j) * (size_t)N;

    for (int k0 = kq * 4; k0 + 3 < N; k0 += 128) {
        // 12 consecutive floats = positions of k0..k0+3 (48B offset is 16B-aligned)
        const float4* pk4 = reinterpret_cast<const float4*>(pb + (size_t)k0 * 3);
        const float4 q0 = pk4[0];
        const float4 q1 = pk4[1];
        const float4 q2 = pk4[2];
        const float4 d4 = *reinterpret_cast<const float4*>(drow + k0);

        const float kx[4] = {q0.x, q0.w, q1.z, q2.y};
        const float ky[4] = {q0.y, q1.x, q1.w, q2.z};
        const float kz[4] = {q0.z, q1.y, q2.x, q2.w};
        const float dk[4] = {d4.x, d4.y, d4.z, d4.w};

        float r[4];
#pragma unroll
        for (int u = 0; u < 4; ++u) {
            const float fx = kx[u] - pix;
            const float fy = ky[u] - piy;
            const float fz = kz[u] - piz;
            r[u] = angle_one(ex, ey, ez, fx, fy, fz, dij, dk[u], i, j, k0 + u);
        }
        float4 res = make_float4(r[0], r[1], r[2], r[3]);
        *reinterpret_cast<float4*>(orow + k0) = res;
    }
}

// Generic scalar fallback (any N), grid-stride over all B*N^3 elements.
__global__ void angle_scalar(const float* __restrict__ pos,
                             const float* __restrict__ dist,
                             float* __restrict__ out, int N, long long total) {
    const long long NN  = (long long)N * N;
    const long long NNN = NN * N;
    for (long long idx = (long long)blockIdx.x * blockDim.x + threadIdx.x;
         idx < total; idx += (long long)gridDim.x * blockDim.x) {
        int k = (int)(idx % N);
        int j = (int)((idx / N) % N);
        int i = (int)((idx / NN) % N);
        int b = (int)(idx / NNN);

        const float* pb   = pos  + (size_t)b * N * 3;
        const float* drow = dist + ((size_t)b * N + i) * N;

        float pix = pb[i * 3 + 0], piy = pb[i * 3 + 1], piz = pb[i * 3 + 2];
        float ex = pb[j * 3 + 0] - pix, ey = pb[j * 3 + 1] - piy, ez = pb[j * 3 + 2] - piz;
        float fx = pb[k * 3 + 0] - pix, fy = pb[k * 3 + 1] - piy, fz = pb[k * 3 + 2] - piz;
        out[idx] = angle_one(ex, ey, ez, fx, fy, fz, drow[j], drow[k], i, j, k);
    }
}

extern "C" void kernel_launch(void* const* d_in, const int* in_sizes, int n_in,
                              void* d_out, int out_size, void* d_ws, size_t ws_size,
                              hipStream_t stream) {
    const float* pos  = (const float*)d_in[0];
    const float* dist = (const float*)d_in[1];
    float* out = (float*)d_out;

    const long long pos_sz  = in_sizes[0];  // B*N*3
    const long long dist_sz = in_sizes[1];  // B*N*N
    const int N = (int)((3LL * dist_sz) / pos_sz);
    const int B = (int)(pos_sz / (3LL * (long long)N));

    if (N > 0 && (N % 4) == 0) {
        dim3 grid((N + 7) / 8, N, B);
        angle_vec4<<<grid, dim3(256), 0, stream>>>(pos, dist, out, N);
    } else {
        const long long total = (long long)B * N * N * N;
        int blocks = (int)((total + 255) / 256);
        if (blocks > 131072) blocks = 131072;
        if (blocks < 1) blocks = 1;
        angle_scalar<<<blocks, dim3(256), 0, stream>>>(pos, dist, out, N, total);
    }
}

// Round 2
// 26.212 us; speedup vs baseline: 1.0406x; 1.0406x over previous
//
#include <hip/hip_runtime.h>
#include <hip/hip_bf16.h>

// AngleTensor: out[b,i,j,k] = mask * arccos( (p_j - p_i) . (p_k - p_i) / (d_ij * d_ik) )
// mask = 0 when i==j || i==k || j==k; mag < 1e-10 -> mag = 1.
// positions: (B,N,3) f32, dist: (B,N,N) f32, out: (B,N,N,N) f32.

#define EPSV 1e-10f
#define PI_F 3.14159265358979323846f

// Abramowitz-Stegun 4.4.45: |err| <= ~7e-5 rad on [0,1]; reflected for x<0.
__device__ __forceinline__ float fast_acos(float x) {
    float ax = fabsf(x);
    float p = fmaf(ax, -0.0187293f, 0.0742610f);
    p = fmaf(ax, p, -0.2121144f);
    p = fmaf(ax, p, 1.5707288f);
    float s = sqrtf(fmaxf(1.0f - ax, 0.0f));
    float r = s * p;
    return (x < 0.0f) ? (PI_F - r) : r;
}

// Per-element math: bitwise-identical to the round-1 passing kernel.
__device__ __forceinline__ float angle_core(float ex, float ey, float ez,
                                            float fx, float fy, float fz,
                                            float dij, float dik, bool msk) {
    float dot = fmaf(ex, fx, fmaf(ey, fy, ez * fz));
    float mag = dij * dik;
    mag = (mag < EPSV) ? 1.0f : mag;
    float c = dot * __builtin_amdgcn_rcpf(mag);
    c = fminf(fmaxf(c, -1.0f), 1.0f);
    float ang = fast_acos(c);
    return msk ? ang : 0.0f;
}

// Persistent-per-(b,i) tiled kernel. Requires N % 4 == 0.
// Block = 256 threads handles one (b,i) for a strided subset of j-rows.
// LDS: f_k = p_k - p_i (3 arrays) + d_ik, staged once, reused for all rows.
// Each 32-lane quarter (jj = tid>>5) owns row j = jj + 8*s (+ 8*gridDim.z steps);
// lane kq = tid&31 covers k = 4*kq..4*kq+3 (+128 steps) -> one float4 store each.
__global__ __launch_bounds__(256) void angle_tiled(const float* __restrict__ pos,
                                                   const float* __restrict__ dist,
                                                   float* __restrict__ out, int N) {
    extern __shared__ float smem[];
    float* sfx = smem;
    float* sfy = smem + N;
    float* sfz = smem + 2 * N;
    float* sdk = smem + 3 * N;

    const int i = blockIdx.x;
    const int b = blockIdx.y;
    const int s = blockIdx.z;
    const int jstep = 8 * gridDim.z;

    const float* pb   = pos  + (size_t)b * N * 3;
    const float* drow = dist + ((size_t)b * N + i) * N;

    const float pix = pb[3 * i + 0];
    const float piy = pb[3 * i + 1];
    const float piz = pb[3 * i + 2];

    for (int t = threadIdx.x; t < N; t += blockDim.x) {
        sfx[t] = pb[3 * t + 0] - pix;
        sfy[t] = pb[3 * t + 1] - piy;
        sfz[t] = pb[3 * t + 2] - piz;
        sdk[t] = drow[t];
    }
    __syncthreads();

    const int kq = threadIdx.x & 31;
    const int jj = threadIdx.x >> 5;

    for (int j = jj + 8 * s; j < N; j += jstep) {
        const float ex  = sfx[j];   // same-address LDS broadcast within the quarter
        const float ey  = sfy[j];
        const float ez  = sfz[j];
        const float dij = sdk[j];
        const bool  jne = (j != i);
        float* orow = out + (((size_t)b * N + i) * (size_t)N + j) * (size_t)N;

        for (int k0 = kq * 4; k0 + 3 < N; k0 += 128) {
            // 16B-aligned LDS vector reads (k0 % 4 == 0)
            const float4 vx = *reinterpret_cast<const float4*>(&sfx[k0]);
            const float4 vy = *reinterpret_cast<const float4*>(&sfy[k0]);
            const float4 vz = *reinterpret_cast<const float4*>(&sfz[k0]);
            const float4 vd = *reinterpret_cast<const float4*>(&sdk[k0]);

            const float fx[4] = {vx.x, vx.y, vx.z, vx.w};
            const float fy[4] = {vy.x, vy.y, vy.z, vy.w};
            const float fz[4] = {vz.x, vz.y, vz.z, vz.w};
            const float dk[4] = {vd.x, vd.y, vd.z, vd.w};

            float r[4];
#pragma unroll
            for (int u = 0; u < 4; ++u) {
                const int k = k0 + u;
                const bool msk = jne && (k != i) && (k != j);
                r[u] = angle_core(ex, ey, ez, fx[u], fy[u], fz[u], dij, dk[u], msk);
            }
            *reinterpret_cast<float4*>(orow + k0) = make_float4(r[0], r[1], r[2], r[3]);
        }
    }
}

// Generic scalar fallback (any N), grid-stride over all B*N^3 elements.
__global__ void angle_scalar(const float* __restrict__ pos,
                             const float* __restrict__ dist,
                             float* __restrict__ out, int N, long long total) {
    const long long NN  = (long long)N * N;
    const long long NNN = NN * N;
    for (long long idx = (long long)blockIdx.x * blockDim.x + threadIdx.x;
         idx < total; idx += (long long)gridDim.x * blockDim.x) {
        int k = (int)(idx % N);
        int j = (int)((idx / N) % N);
        int i = (int)((idx / NN) % N);
        int b = (int)(idx / NNN);

        const float* pb   = pos  + (size_t)b * N * 3;
        const float* drow = dist + ((size_t)b * N + i) * N;

        float pix = pb[i * 3 + 0], piy = pb[i * 3 + 1], piz = pb[i * 3 + 2];
        float ex = pb[j * 3 + 0] - pix, ey = pb[j * 3 + 1] - piy, ez = pb[j * 3 + 2] - piz;
        float fx = pb[k * 3 + 0] - pix, fy = pb[k * 3 + 1] - piy, fz = pb[k * 3 + 2] - piz;
        bool msk = (i != j) && (i != k) && (j != k);
        out[idx] = angle_core(ex, ey, ez, fx, fy, fz, drow[j], drow[k], msk);
    }
}

extern "C" void kernel_launch(void* const* d_in, const int* in_sizes, int n_in,
                              void* d_out, int out_size, void* d_ws, size_t ws_size,
                              hipStream_t stream) {
    const float* pos  = (const float*)d_in[0];
    const float* dist = (const float*)d_in[1];
    float* out = (float*)d_out;

    const long long pos_sz  = in_sizes[0];  // B*N*3
    const long long dist_sz = in_sizes[1];  // B*N*N
    const int N = (int)((3LL * dist_sz) / pos_sz);
    const int B = (int)(pos_sz / (3LL * (long long)N));

    if (N > 0 && (N % 4) == 0 && N <= 2048) {
        const int SPLIT = 2;                       // 2048 blocks -> 8 blocks/CU -> 32 waves/CU
        dim3 grid(N, B, SPLIT);
        size_t smem = (size_t)4 * N * sizeof(float);
        angle_tiled<<<grid, dim3(256), smem, stream>>>(pos, dist, out, N);
    } else {
        const long long total = (long long)B * N * N * N;
        int blocks = (int)((total + 255) / 256);
        if (blocks > 131072) blocks = 131072;
        if (blocks < 1) blocks = 1;
        angle_scalar<<<blocks, dim3(256), 0, stream>>>(pos, dist, out, N, total);
    }
}

// Round 3
// 19.070 us; speedup vs baseline: 1.4303x; 1.3745x over previous
//
#include <hip/hip_runtime.h>
#include <hip/hip_bf16.h>

// AngleTensor: out[b,i,j,k] = mask * arccos( (p_j - p_i) . (p_k - p_i) / (d_ij * d_ik) )
// mask = 0 when i==j || i==k || j==k; mag < 1e-10 -> mag = 1.
// positions: (B,N,3) f32, dist: (B,N,N) f32, out: (B,N,N,N) f32.

#define EPSV 1e-10f
#define PI_F 3.14159265358979323846f

// Abramowitz-Stegun 4.4.45 acos, input pre-clamped to [-1,1].
// c == 1 (masked elements) -> exact 0: s = sqrt(1-1) = 0, r = 0, c > 0 branch.
__device__ __forceinline__ float acos_clamped(float c) {
    float ax = fabsf(c);
    float p = fmaf(ax, -0.0187293f, 0.0742610f);
    p = fmaf(ax, p, -0.2121144f);
    p = fmaf(ax, p, 1.5707288f);
    float s = __builtin_amdgcn_sqrtf(1.0f - ax);   // ax <= 1 guaranteed
    float r = s * p;
    return (c < 0.0f) ? (PI_F - r) : r;
}

__device__ __forceinline__ float angle_elem(float ex, float ey, float ez, float dij,
                                            float fx, float fy, float fz, float dik,
                                            bool valid) {
    float dot = fmaf(ex, fx, fmaf(ey, fy, ez * fz));
    float mag = dij * dik;
    mag = (mag < EPSV) ? 1.0f : mag;
    float c = dot * __builtin_amdgcn_rcpf(mag);
    c = __builtin_amdgcn_fmed3f(c, -1.0f, 1.0f);   // clamp
    c = valid ? c : 1.0f;                          // masked -> acos gives exact 0
    return acos_clamped(c);
}

// Register-resident kernel for N % 4 == 0, N <= 128.
// Block = 256 threads handles one (b,i); quarter jj owns rows j = jj + 8*s + 16*t;
// lane kq = tid&31 owns k = 4*kq..4*kq+3 held in 16 VGPRs for the whole j-loop.
__global__ __launch_bounds__(256) void angle_reg(const float* __restrict__ pos,
                                                 const float* __restrict__ dist,
                                                 float* __restrict__ out, int N) {
    extern __shared__ float smem[];
    float* sfx = smem;
    float* sfy = smem + N;
    float* sfz = smem + 2 * N;
    float* sdk = smem + 3 * N;

    const int i = blockIdx.x;
    const int b = blockIdx.y;
    const int s = blockIdx.z;

    const float* pb   = pos  + (size_t)b * N * 3;
    const float* drow = dist + ((size_t)b * N + i) * N;

    const float pix = pb[3 * i + 0];
    const float piy = pb[3 * i + 1];
    const float piz = pb[3 * i + 2];

    for (int t = threadIdx.x; t < N; t += blockDim.x) {
        sfx[t] = pb[3 * t + 0] - pix;
        sfy[t] = pb[3 * t + 1] - piy;
        sfz[t] = pb[3 * t + 2] - piz;
        sdk[t] = drow[t];
    }
    __syncthreads();

    const int kq = threadIdx.x & 31;
    const int jj = threadIdx.x >> 5;
    const int k0 = kq * 4;
    const bool klive = (k0 + 3 < N);

    // k-operands pinned in registers for the whole kernel.
    float4 kx = make_float4(0, 0, 0, 0), ky = kx, kz = kx, kd = kx;
    if (klive) {
        kx = *reinterpret_cast<const float4*>(&sfx[k0]);
        ky = *reinterpret_cast<const float4*>(&sfy[k0]);
        kz = *reinterpret_cast<const float4*>(&sfz[k0]);
        kd = *reinterpret_cast<const float4*>(&sdk[k0]);
    }
    // (k != i) masks: j-invariant, hoisted.
    const bool ki0 = (k0 + 0) != i;
    const bool ki1 = (k0 + 1) != i;
    const bool ki2 = (k0 + 2) != i;
    const bool ki3 = (k0 + 3) != i;

    float* obase = out + ((size_t)b * N + i) * (size_t)N * (size_t)N;

    auto do_row = [&](int j) {
        const float ex  = sfx[j];
        const float ey  = sfy[j];
        const float ez  = sfz[j];
        const float dij = sdk[j];
        const bool  jne = (j != i);
        float4 r;
        r.x = angle_elem(ex, ey, ez, dij, kx.x, ky.x, kz.x, kd.x, jne && ki0 && (k0 + 0 != j));
        r.y = angle_elem(ex, ey, ez, dij, kx.y, ky.y, kz.y, kd.y, jne && ki1 && (k0 + 1 != j));
        r.z = angle_elem(ex, ey, ez, dij, kx.z, ky.z, kz.z, kd.z, jne && ki2 && (k0 + 2 != j));
        r.w = angle_elem(ex, ey, ez, dij, kx.w, ky.w, kz.w, kd.w, jne && ki3 && (k0 + 3 != j));
        if (klive)
            *reinterpret_cast<float4*>(obase + (size_t)j * N + k0) = r;
    };

    // rows j = jj + 8*s + 16*t, unrolled x2 for broadcast-latency overlap.
    for (int j = jj + 8 * s; j < N; j += 32) {
        do_row(j);
        if (j + 16 < N) do_row(j + 16);
    }
}

// Generic scalar fallback (any N), grid-stride over all B*N^3 elements.
__global__ void angle_scalar(const float* __restrict__ pos,
                             const float* __restrict__ dist,
                             float* __restrict__ out, int N, long long total) {
    const long long NN  = (long long)N * N;
    const long long NNN = NN * N;
    for (long long idx = (long long)blockIdx.x * blockDim.x + threadIdx.x;
         idx < total; idx += (long long)gridDim.x * blockDim.x) {
        int k = (int)(idx % N);
        int j = (int)((idx / N) % N);
        int i = (int)((idx / NN) % N);
        int b = (int)(idx / NNN);

        const float* pb   = pos  + (size_t)b * N * 3;
        const float* drow = dist + ((size_t)b * N + i) * N;

        float pix = pb[i * 3 + 0], piy = pb[i * 3 + 1], piz = pb[i * 3 + 2];
        float ex = pb[j * 3 + 0] - pix, ey = pb[j * 3 + 1] - piy, ez = pb[j * 3 + 2] - piz;
        float fx = pb[k * 3 + 0] - pix, fy = pb[k * 3 + 1] - piy, fz = pb[k * 3 + 2] - piz;
        bool msk = (i != j) && (i != k) && (j != k);
        out[idx] = angle_elem(ex, ey, ez, drow[j], fx, fy, fz, drow[k], msk);
    }
}

extern "C" void kernel_launch(void* const* d_in, const int* in_sizes, int n_in,
                              void* d_out, int out_size, void* d_ws, size_t ws_size,
                              hipStream_t stream) {
    const float* pos  = (const float*)d_in[0];
    const float* dist = (const float*)d_in[1];
    float* out = (float*)d_out;

    const long long pos_sz  = in_sizes[0];  // B*N*3
    const long long dist_sz = in_sizes[1];  // B*N*N
    const int N = (int)((3LL * dist_sz) / pos_sz);
    const int B = (int)(pos_sz / (3LL * (long long)N));

    if (N > 0 && (N % 4) == 0 && N <= 128) {
        const int SPLIT = 2;                       // grid = 2048 blocks for B=8,N=128
        dim3 grid(N, B, SPLIT);
        size_t smem = (size_t)4 * N * sizeof(float);
        angle_reg<<<grid, dim3(256), smem, stream>>>(pos, dist, out, N);
    } else {
        const long long total = (long long)B * N * N * N;
        int blocks = (int)((total + 255) / 256);
        if (blocks > 131072) blocks = 131072;
        if (blocks < 1) blocks = 1;
        angle_scalar<<<blocks, dim3(256), 0, stream>>>(pos, dist, out, N, total);
    }
}

// Round 5
// 17.270 us; speedup vs baseline: 1.5795x; 1.1042x over previous
//
#include <hip/hip_runtime.h>
#include <hip/hip_bf16.h>

// AngleTensor: out[b,i,j,k] = mask * arccos( (p_j - p_i) . (p_k - p_i) / (d_ij * d_ik) )
// mask = 0 when i==j || i==k || j==k; mag < 1e-10 -> mag = 1.
// positions: (B,N,3) f32, dist: (B,N,N) f32, out: (B,N,N,N) f32.
//
// Algebraic form used here: cos = u_j . u_k with u_t = (p_t - p_i) * rcp(max(d_it, 1e-7)).
// - j==k (i!=j): c = |u_j|^2 = 1 +- ulp -> clamp -> acos ~ 0  (mask handled arithmetically)
// - i==j or i==k: forced to c=1 -> acos = 0 via the j-invariant select (jne && k!=i).

#define PI_F 3.14159265358979323846f

typedef float f32x4 __attribute__((ext_vector_type(4)));  // native vec for nontemporal store

// Abramowitz-Stegun 4.4.45 acos, input pre-clamped to [-1,1]; c==1 -> exact 0.
__device__ __forceinline__ float acos_clamped(float c) {
    float ax = fabsf(c);
    float p = fmaf(ax, -0.0187293f, 0.0742610f);
    p = fmaf(ax, p, -0.2121144f);
    p = fmaf(ax, p, 1.5707288f);
    float s = __builtin_amdgcn_sqrtf(1.0f - ax);   // ax <= 1 guaranteed
    float r = s * p;
    return (c < 0.0f) ? (PI_F - r) : r;
}

__device__ __forceinline__ float angle_dot(float ujx, float ujy, float ujz,
                                           float ukx, float uky, float ukz,
                                           bool valid) {
    float c = fmaf(ujx, ukx, fmaf(ujy, uky, ujz * ukz));
    c = __builtin_amdgcn_fmed3f(c, -1.0f, 1.0f);   // clamp
    c = valid ? c : 1.0f;                          // masked -> acos gives exact 0
    return acos_clamped(c);
}

// Register-resident kernel for N % 4 == 0, N <= 128.
// Block = 256 threads handles one (b,i); quarter jj owns rows j = jj + 8*s + 16*t;
// lane kq = tid&31 owns k = 4*kq..4*kq+3, unit vectors held in 12 VGPRs throughout.
__global__ __launch_bounds__(256) void angle_unit(const float* __restrict__ pos,
                                                  const float* __restrict__ dist,
                                                  float* __restrict__ out, int N) {
    extern __shared__ float smem[];
    float* sux = smem;
    float* suy = smem + N;
    float* suz = smem + 2 * N;

    const int i = blockIdx.x;
    const int b = blockIdx.y;
    const int s = blockIdx.z;

    const float* pb   = pos  + (size_t)b * N * 3;
    const float* drow = dist + ((size_t)b * N + i) * N;

    const float pix = pb[3 * i + 0];
    const float piy = pb[3 * i + 1];
    const float piz = pb[3 * i + 2];

    for (int t = threadIdx.x; t < N; t += blockDim.x) {
        const float dx = pb[3 * t + 0] - pix;
        const float dy = pb[3 * t + 1] - piy;
        const float dz = pb[3 * t + 2] - piz;
        const float r  = __builtin_amdgcn_rcpf(fmaxf(drow[t], 1e-7f));
        sux[t] = dx * r;   // t == i: dx=0 exactly -> u = 0 (handled by mask select)
        suy[t] = dy * r;
        suz[t] = dz * r;
    }
    __syncthreads();

    const int kq = threadIdx.x & 31;
    const int jj = threadIdx.x >> 5;
    const int k0 = kq * 4;
    const bool klive = (k0 + 3 < N);

    // k unit vectors pinned in registers.
    float4 kx = make_float4(0, 0, 0, 0), ky = kx, kz = kx;
    if (klive) {
        kx = *reinterpret_cast<const float4*>(&sux[k0]);
        ky = *reinterpret_cast<const float4*>(&suy[k0]);
        kz = *reinterpret_cast<const float4*>(&suz[k0]);
    }
    // (k != i): j-invariant, hoisted.
    const bool ki0 = (k0 + 0) != i;
    const bool ki1 = (k0 + 1) != i;
    const bool ki2 = (k0 + 2) != i;
    const bool ki3 = (k0 + 3) != i;

    float* obase = out + ((size_t)b * N + i) * (size_t)N * (size_t)N;

    auto do_row = [&](int j) {
        const float ujx = sux[j];   // same-address LDS broadcast within the quarter
        const float ujy = suy[j];
        const float ujz = suz[j];
        const bool  jne = (j != i);
        f32x4 r;
        r.x = angle_dot(ujx, ujy, ujz, kx.x, ky.x, kz.x, jne && ki0);
        r.y = angle_dot(ujx, ujy, ujz, kx.y, ky.y, kz.y, jne && ki1);
        r.z = angle_dot(ujx, ujy, ujz, kx.z, ky.z, kz.z, jne && ki2);
        r.w = angle_dot(ujx, ujy, ujz, kx.w, ky.w, kz.w, jne && ki3);
        if (klive) {
            f32x4* dst = reinterpret_cast<f32x4*>(obase + (size_t)j * N + k0);
            __builtin_nontemporal_store(r, dst);   // write-once output, bypass L2 alloc
        }
    };

    // rows j = jj + 8*s + 16*t, unrolled x2 for broadcast-latency overlap.
    for (int j = jj + 8 * s; j < N; j += 32) {
        do_row(j);
        if (j + 16 < N) do_row(j + 16);
    }
}

// Generic scalar fallback (any N), grid-stride over all B*N^3 elements.
__global__ void angle_scalar(const float* __restrict__ pos,
                             const float* __restrict__ dist,
                             float* __restrict__ out, int N, long long total) {
    const long long NN  = (long long)N * N;
    const long long NNN = NN * N;
    for (long long idx = (long long)blockIdx.x * blockDim.x + threadIdx.x;
         idx < total; idx += (long long)gridDim.x * blockDim.x) {
        int k = (int)(idx % N);
        int j = (int)((idx / N) % N);
        int i = (int)((idx / NN) % N);
        int b = (int)(idx / NNN);

        const float* pb   = pos  + (size_t)b * N * 3;
        const float* drow = dist + ((size_t)b * N + i) * N;

        float pix = pb[i * 3 + 0], piy = pb[i * 3 + 1], piz = pb[i * 3 + 2];
        float rj = __builtin_amdgcn_rcpf(fmaxf(drow[j], 1e-7f));
        float rk = __builtin_amdgcn_rcpf(fmaxf(drow[k], 1e-7f));
        float ujx = (pb[j * 3 + 0] - pix) * rj, ujy = (pb[j * 3 + 1] - piy) * rj,
              ujz = (pb[j * 3 + 2] - piz) * rj;
        float ukx = (pb[k * 3 + 0] - pix) * rk, uky = (pb[k * 3 + 1] - piy) * rk,
              ukz = (pb[k * 3 + 2] - piz) * rk;
        bool valid = (i != j) && (i != k);
        out[idx] = angle_dot(ujx, ujy, ujz, ukx, uky, ukz, valid);
    }
}

extern "C" void kernel_launch(void* const* d_in, const int* in_sizes, int n_in,
                              void* d_out, int out_size, void* d_ws, size_t ws_size,
                              hipStream_t stream) {
    const float* pos  = (const float*)d_in[0];
    const float* dist = (const float*)d_in[1];
    float* out = (float*)d_out;

    const long long pos_sz  = in_sizes[0];  // B*N*3
    const long long dist_sz = in_sizes[1];  // B*N*N
    const int N = (int)((3LL * dist_sz) / pos_sz);
    const int B = (int)(pos_sz / (3LL * (long long)N));

    if (N > 0 && (N % 4) == 0 && N <= 128) {
        const int SPLIT = 2;                       // grid = 2048 blocks for B=8,N=128
        dim3 grid(N, B, SPLIT);
        size_t smem = (size_t)3 * N * sizeof(float);
        angle_unit<<<grid, dim3(256), smem, stream>>>(pos, dist, out, N);
    } else {
        const long long total = (long long)B * N * N * N;
        int blocks = (int)((total + 255) / 256);
        if (blocks > 131072) blocks = 131072;
        if (blocks < 1) blocks = 1;
        angle_scalar<<<blocks, dim3(256), 0, stream>>>(pos, dist, out, N, total);
    }
}